// Round 1
// baseline (253.147 us; speedup 1.0000x reference)
//
#include <hip/hip_runtime.h>

#define DEV __device__ __forceinline__

DEV float fexp2(float x) { return __builtin_amdgcn_exp2f(x); }
DEV float frcp(float x) { return __builtin_amdgcn_rcpf(x); }

// Broadcast lane (quad_base + S) to all 4 lanes of the quad via DPP quad_perm.
template <int S>
DEV float qbcast(float x) {
#if __has_builtin(__builtin_amdgcn_update_dpp)
  int i = __float_as_int(x);
  i = __builtin_amdgcn_update_dpp(0, i, S * 0x55, 0xF, 0xF, true);
  return __int_as_float(i);
#else
  return __shfl(x, S, 4);
#endif
}

struct Cell {
  float wih[5][5];
  float whh[5][5];
  float b[5];
};

DEV void load_cell(Cell& W, const float* __restrict__ Wih,
                   const float* __restrict__ Whh, const float* __restrict__ bih,
                   const float* __restrict__ bhh, int s) {
#pragma unroll
  for (int j = 0; j < 5; ++j) {
    int r = 5 * s + j;
#pragma unroll
    for (int k = 0; k < 5; ++k) {
      W.wih[j][k] = Wih[r * 5 + k];
      W.whh[j][k] = Whh[r * 5 + k];
    }
    W.b[j] = bih[r] + bhh[r];
  }
}

// One LSTM cell step. Lane s of each quad computes gate group s (i,f,g,o).
// kexp/m2/a2 unify sigmoid (s!=2) and tanh (s==2):
//   act(x) = m2 * rcp(1 + exp2(kexp*x)) + a2
DEV void cell_step(const Cell& W, float kexp, float m2, float a2,
                   const float x[5], float h[5], float c[5]) {
  float a[5];
#pragma unroll
  for (int j = 0; j < 5; ++j) {
    float acc = W.b[j];
#pragma unroll
    for (int k = 0; k < 5; ++k) acc = fmaf(W.wih[j][k], x[k], acc);
#pragma unroll
    for (int k = 0; k < 5; ++k) acc = fmaf(W.whh[j][k], h[k], acc);
    float e = fexp2(acc * kexp);
    float r = frcp(1.0f + e);
    a[j] = fmaf(m2, r, a2);
  }
// Share activated gates across the quad; every lane redundantly updates c,h
// (redundancy across lanes of the same instruction is free in issue cycles).
#pragma unroll
  for (int j = 0; j < 5; ++j) {
    float I = qbcast<0>(a[j]);
    float F = qbcast<1>(a[j]);
    float G = qbcast<2>(a[j]);
    float O = qbcast<3>(a[j]);
    float cj = fmaf(F, c[j], I * G);
    c[j] = cj;
    float e2 = fexp2(cj * -2.885390082f);  // tanh(c)
    float tc = fmaf(2.0f, frcp(1.0f + e2), -1.0f);
    h[j] = O * tc;
  }
}

DEV void lds_copy(float* dst, const float* __restrict__ src, int n, int tid) {
  for (int i = tid; i < n; i += 256) dst[i] = src[i];
}

// LDS layout for FC weights (floats): W1@0(640) b1@640(32) W2@672(1024)
// b2@1696(32) W3@1728(512) b3@2240(16) W4@2256(256) b4@2512(16) W5@2528(80)
// b5@2608(5). Total 2613 floats = 10452 B.
__global__ __launch_bounds__(256, 1) void rnn_fused_kernel(
    const float* __restrict__ x1, const float* __restrict__ x2,
    const float* __restrict__ Wih1, const float* __restrict__ Whh1,
    const float* __restrict__ bih1, const float* __restrict__ bhh1,
    const float* __restrict__ Wih2a, const float* __restrict__ Whh2a,
    const float* __restrict__ bih2a, const float* __restrict__ bhh2a,
    const float* __restrict__ Wih2b, const float* __restrict__ Whh2b,
    const float* __restrict__ bih2b, const float* __restrict__ bhh2b,
    const float* __restrict__ W1, const float* __restrict__ b1,
    const float* __restrict__ W2, const float* __restrict__ b2,
    const float* __restrict__ W3, const float* __restrict__ b3,
    const float* __restrict__ W4, const float* __restrict__ b4,
    const float* __restrict__ W5, const float* __restrict__ b5,
    float* __restrict__ out, int B) {
  __shared__ __align__(16) float sFC[2613];
  {
    int tl = threadIdx.x;
    lds_copy(sFC + 0, W1, 640, tl);
    lds_copy(sFC + 640, b1, 32, tl);
    lds_copy(sFC + 672, W2, 1024, tl);
    lds_copy(sFC + 1696, b2, 32, tl);
    lds_copy(sFC + 1728, W3, 512, tl);
    lds_copy(sFC + 2240, b3, 16, tl);
    lds_copy(sFC + 2256, W4, 256, tl);
    lds_copy(sFC + 2512, b4, 16, tl);
    lds_copy(sFC + 2528, W5, 80, tl);
    lds_copy(sFC + 2608, b5, 5, tl);
  }
  __syncthreads();

  int tid = blockIdx.x * 256 + threadIdx.x;
  int e = tid >> 2;  // batch element (4 consecutive lanes per element)
  int s = tid & 3;   // gate group: 0=i 1=f 2=g 3=o
  if (e >= B) return;

  Cell WA, WB, WC;
  load_cell(WA, Wih1, Whh1, bih1, bhh1, s);
  load_cell(WB, Wih2a, Whh2a, bih2a, bhh2a, s);
  load_cell(WC, Wih2b, Whh2b, bih2b, bhh2b, s);

  const float kexp = (s == 2) ? -2.885390082f : -1.442695041f;
  const float m2 = (s == 2) ? 2.0f : 1.0f;
  const float a2 = (s == 2) ? -1.0f : 0.0f;

  const float* px1 = x1 + (size_t)e * 640;
  const float* px2 = x2 + (size_t)e * 640;

  float h1[5], c1[5], h2a[5], c2a[5], h2b[5], c2b[5];
#pragma unroll
  for (int k = 0; k < 5; ++k) {
    h1[k] = c1[k] = h2a[k] = c2a[k] = h2b[k] = c2b[k] = 0.0f;
  }

  float xa[5], xb[5];
#pragma unroll
  for (int k = 0; k < 5; ++k) {
    xa[k] = px1[k];
    xb[k] = px2[k];
  }

  for (int t = 0; t < 128; ++t) {
    // Prefetch next step's inputs (clamped) to hide load latency.
    int tn = (t < 127) ? t + 1 : 127;
    float nxa[5], nxb[5];
#pragma unroll
    for (int k = 0; k < 5; ++k) {
      nxa[k] = px1[tn * 5 + k];
      nxb[k] = px2[tn * 5 + k];
    }
    cell_step(WA, kexp, m2, a2, xa, h1, c1);
    cell_step(WB, kexp, m2, a2, xb, h2a, c2a);
    cell_step(WC, kexp, m2, a2, h2a, h2b, c2b);  // lstm2b consumes h2a at t
#pragma unroll
    for (int k = 0; k < 5; ++k) {
      xa[k] = nxa[k];
      xb[k] = nxb[k];
    }
  }

  // FC stack (all 4 lanes redundantly; SIMT makes this free in issue cycles).
  float in0[20];
#pragma unroll
  for (int k = 0; k < 5; ++k) {
    in0[k] = xa[k];        // x1[:, -1, :]
    in0[5 + k] = xb[k];    // x2[:, -1, :]
    in0[10 + k] = h1[k];   // out1
    in0[15 + k] = h2b[k];  // out2
  }
  float v1[32];
#pragma unroll
  for (int n = 0; n < 32; ++n) {
    float acc = sFC[640 + n];
#pragma unroll
    for (int k = 0; k < 20; ++k) acc = fmaf(sFC[n * 20 + k], in0[k], acc);
    v1[n] = fmaxf(acc, 0.0f);
  }
  float v2[32];
#pragma unroll
  for (int n = 0; n < 32; ++n) {
    float acc = sFC[1696 + n];
#pragma unroll
    for (int k = 0; k < 32; ++k) acc = fmaf(sFC[672 + n * 32 + k], v1[k], acc);
    v2[n] = fmaxf(acc, 0.0f);
  }
  float v3[16];
#pragma unroll
  for (int n = 0; n < 16; ++n) {
    float acc = sFC[2240 + n];
#pragma unroll
    for (int k = 0; k < 32; ++k) acc = fmaf(sFC[1728 + n * 32 + k], v2[k], acc);
    v3[n] = fmaxf(acc, 0.0f);
  }
  float v4[16];
#pragma unroll
  for (int n = 0; n < 16; ++n) {
    float acc = sFC[2512 + n];
#pragma unroll
    for (int k = 0; k < 16; ++k) acc = fmaf(sFC[2256 + n * 16 + k], v3[k], acc);
    v4[n] = fmaxf(acc, 0.0f);
  }
  if (s == 0) {
#pragma unroll
    for (int n = 0; n < 5; ++n) {
      float acc = sFC[2608 + n];
#pragma unroll
      for (int k = 0; k < 16; ++k)
        acc = fmaf(sFC[2528 + n * 16 + k], v4[k], acc);
      out[(size_t)e * 5 + n] = acc;
    }
  }
}

extern "C" void kernel_launch(void* const* d_in, const int* in_sizes, int n_in,
                              void* d_out, int out_size, void* d_ws,
                              size_t ws_size, hipStream_t stream) {
  const float* x1 = (const float*)d_in[0];
  const float* x2 = (const float*)d_in[1];
  const float* Wih1 = (const float*)d_in[2];
  const float* Whh1 = (const float*)d_in[3];
  const float* bih1 = (const float*)d_in[4];
  const float* bhh1 = (const float*)d_in[5];
  const float* Wih2a = (const float*)d_in[6];
  const float* Whh2a = (const float*)d_in[7];
  const float* bih2a = (const float*)d_in[8];
  const float* bhh2a = (const float*)d_in[9];
  const float* Wih2b = (const float*)d_in[10];
  const float* Whh2b = (const float*)d_in[11];
  const float* bih2b = (const float*)d_in[12];
  const float* bhh2b = (const float*)d_in[13];
  const float* W1 = (const float*)d_in[14];
  const float* b1 = (const float*)d_in[15];
  const float* W2 = (const float*)d_in[16];
  const float* b2 = (const float*)d_in[17];
  const float* W3 = (const float*)d_in[18];
  const float* b3 = (const float*)d_in[19];
  const float* W4 = (const float*)d_in[20];
  const float* b4 = (const float*)d_in[21];
  const float* W5 = (const float*)d_in[22];
  const float* b5 = (const float*)d_in[23];

  int B = in_sizes[0] / 640;  // [B, 128, 5]
  int threads = B * 4;
  int blocks = (threads + 255) / 256;

  rnn_fused_kernel<<<blocks, 256, 0, stream>>>(
      x1, x2, Wih1, Whh1, bih1, bhh1, Wih2a, Whh2a, bih2a, bhh2a, Wih2b, Whh2b,
      bih2b, bhh2b, W1, b1, W2, b2, W3, b3, W4, b4, W5, b5, (float*)d_out, B);
}